// Round 10
// baseline (580.877 us; speedup 1.0000x reference)
//
#include <hip/hip_runtime.h>
#include <hip/hip_bf16.h>

#define B_ 64
#define S_ 4096
#define H_ 512
#define E_ 512
#define NEG_INF_ -1e10f

typedef __attribute__((ext_vector_type(8))) short short8;
typedef __attribute__((ext_vector_type(16))) float f32x16;

static __device__ __forceinline__ unsigned short f2bf(float f) {
    union { float f; unsigned u; } v; v.f = f;
    unsigned x = v.u;
    x += 0x7FFFu + ((x >> 16) & 1u);   // round-to-nearest-even
    return (unsigned short)(x >> 16);
}

// vendor RNE pair conversion (verified r3/r5-r9: absmax 4.9e-4)
static __device__ __forceinline__ unsigned pk2(float lo, float hi) {
    float2 f; f.x = lo; f.y = hi;
    union { __hip_bfloat162 h; unsigned u; } c;
    c.h = __float22bfloat162_rn(f);
    return c.u;
}

static __device__ __forceinline__ void gload_lds16(const void* g, void* l) {
    __builtin_amdgcn_global_load_lds(
        (const __attribute__((address_space(1))) void*)g,
        (__attribute__((address_space(3))) void*)l, 16, 0, 0);
}

#define VMCNT12 do { asm volatile("s_waitcnt vmcnt(12)" ::: "memory"); __builtin_amdgcn_sched_barrier(0); } while (0)
#define VMCNT6  do { asm volatile("s_waitcnt vmcnt(6)"  ::: "memory"); __builtin_amdgcn_sched_barrier(0); } while (0)
#define VMCNT0  do { asm volatile("s_waitcnt vmcnt(0)"  ::: "memory"); __builtin_amdgcn_sched_barrier(0); } while (0)

// ---------------- prep: Wkt[h][e] = bf16(Wk[e][h]) ----------------
__global__ void prep_wkt(const float* __restrict__ wk, unsigned short* __restrict__ wkt) {
    int idx = blockIdx.x * 256 + threadIdx.x;
    int h = idx >> 9, e = idx & 511;
    wkt[idx] = f2bf(wk[e * H_ + h]);
}

// ---------------- prep: qb[b][h] = hidden[b]@Wq[:,h] + bq[h] + bk[h] ----------------
__global__ void prep_qb(const float* __restrict__ hidden, const float* __restrict__ wq,
                        const float* __restrict__ bq, const float* __restrict__ bk,
                        float* __restrict__ qb) {
    __shared__ float hid[H_];
    int b = blockIdx.x, t = threadIdx.x;           // 256 threads
    hid[t]       = hidden[b * H_ + t];
    hid[t + 256] = hidden[b * H_ + t + 256];
    __syncthreads();
    for (int hh = t; hh < H_; hh += 256) {
        float s = 0.f;
        for (int e = 0; e < H_; ++e) s += hid[e] * wq[e * H_ + hh];
        qb[b * H_ + hh] = s + bq[hh] + bk[hh];
    }
}

// ---------------- main: partial scores over one 128-col n-chunk ----------------
// grid 8192: xcd-chunked -> (b, s-tile 128, n-tile 128). block 256 thr = 4 waves,
// wave w owns M-strip rows w*32..w*32+31 x ALL 128 N-cols (acc[4]).
// A (enc f32): loaded DIRECTLY into each lane's MFMA fragment (row = s0+w*32+l31,
//   k = kc*32+ks*16+g*8) -> pk2 -> af. NO LDS for A (chain: vmcnt->cvt->barrier->dsread->MFMA).
// B (Wkt bf16): global_load_lds DMA, ring-4, XOR layout, source-permuted [r5-r9: 0-conflict].
// Runtime kc loop, depth-3 prefetch, counted vmcnt(12/6/0), one s_barrier per kc (B publish).
__global__ __launch_bounds__(256, 3) void scores_kernel(
    const float* __restrict__ enc, const unsigned short* __restrict__ wkt,
    const float* __restrict__ qb, const float* __restrict__ wv,
    float* __restrict__ part)
{
    __shared__ char lds[32768];   // B0..B3 @ 8KB each; epilogue reuses [0, 19456)

    int id = blockIdx.x;
    int xcd = id & 7, qq = id >> 3;
    int logical = xcd * 1024 + qq;
    int b  = logical >> 7;
    int r  = logical & 127;
    int st = r >> 2, nt = r & 3;
    int s0 = st * 128;

    const int tid  = threadIdx.x;
    const int lane = tid & 63;
    const int wave = tid >> 6;       // M-strip 0..3
    const int l31  = lane & 31;
    const int g    = lane >> 5;

    // A: lane-private fragment row pointer (row = s0 + wave*32 + l31, k base g*8)
    const float* aRow = enc + ((size_t)b * S_ + s0 + wave * 32 + l31) * E_ + g * 8;

    auto loadA = [&](int kc, float4 (&rg)[4]) {
        const float* p = aRow + kc * 32;
        rg[0] = *(const float4*)(p);          // ks=0, k = kc*32+g*8 .. +3
        rg[1] = *(const float4*)(p + 4);      //        .. +7
        rg[2] = *(const float4*)(p + 16);     // ks=1
        rg[3] = *(const float4*)(p + 20);
    };
    // ---- B: 128 n x 32 k bf16 = 8KB DMA; stored [sn 32][16]: sl = ss^(sn&15); n=(sl>>2)*32+sn; k=(sl&3)*8
    auto stageB = [&](int kc, char* buf) {
#pragma unroll
        for (int p = 0; p < 2; ++p) {
            int gi0 = p * 256 + wave * 64;
            char* db = buf + gi0 * 16;                 // wave-uniform dest
            int gi = gi0 + lane;
            int sn = gi >> 4, ss = gi & 15;
            int sl = ss ^ (sn & 15);
            int n  = (sl >> 2) * 32 + sn;
            const unsigned short* gp = wkt + (size_t)(nt * 128 + n) * 512 + kc * 32 + (sl & 3) * 8;
            gload_lds16(gp, db);
        }
    };

    f32x16 acc[4];
#pragma unroll
    for (int nf = 0; nf < 4; ++nf)
#pragma unroll
        for (int e = 0; e < 16; ++e) acc[nf][e] = 0.f;

    float4 ra[4], rb[4], rc[4];

    // prologue: 3 stages in flight, each stage FIFO = [B(2), A(4)] -> 18 vm ops
    stageB(0, lds);                  loadA(0, ra);
    stageB(1, lds + 8192);           loadA(1, rb);
    stageB(2, lds + 16384);          loadA(2, rc);

    auto iter = [&](int kc, float4 (&rg)[4]) {
        if (kc <= 13) { VMCNT12; } else if (kc == 14) { VMCNT6; } else { VMCNT0; }
        // convert A(kc) to fragments (independent of B -> overlaps barrier wait)
        short8 af[2];
        {
            union { short8 s; unsigned u[4]; } u0, u1;
            u0.u[0] = pk2(rg[0].x, rg[0].y); u0.u[1] = pk2(rg[0].z, rg[0].w);
            u0.u[2] = pk2(rg[1].x, rg[1].y); u0.u[3] = pk2(rg[1].z, rg[1].w);
            u1.u[0] = pk2(rg[2].x, rg[2].y); u1.u[1] = pk2(rg[2].z, rg[2].w);
            u1.u[2] = pk2(rg[3].x, rg[3].y); u1.u[3] = pk2(rg[3].z, rg[3].w);
            af[0] = u0.s; af[1] = u1.s;
        }
        __builtin_amdgcn_s_barrier();                  // B(kc) resident
        __builtin_amdgcn_sched_barrier(0);
        if (kc < 13) {                                 // issue stage kc+3: [B, A]
            stageB(kc + 3, lds + ((kc + 3) & 3) * 8192);
            loadA(kc + 3, rg);
        }
        const char* Bb = lds + (kc & 3) * 8192;
#pragma unroll
        for (int ks = 0; ks < 2; ++ks) {
#pragma unroll
            for (int nf = 0; nf < 4; ++nf) {
                int sl = nf * 4 + ks * 2 + g;
                short8 bf = *(const short8*)(Bb + l31 * 256 + ((sl ^ (l31 & 15)) << 4));
                acc[nf] = __builtin_amdgcn_mfma_f32_32x32x16_bf16(af[ks], bf, acc[nf], 0, 0, 0);
            }
        }
    };

    for (int t3 = 0; t3 < 5; ++t3) {
        iter(t3 * 3,     ra);
        iter(t3 * 3 + 1, rb);
        iter(t3 * 3 + 2, rc);
    }
    iter(15, ra);

    // ---- epilogue: p[e] = sum_nf Wv[col]*tanh(qb[col]+acc[nf][e]), col = nt*128+nf*32+l31 ----
    float p[16];
#pragma unroll
    for (int nf = 0; nf < 4; ++nf) {
        int col = nt * 128 + nf * 32 + l31;
        float qv  = qb[b * H_ + col];
        float wvv = wv[col];
#pragma unroll
        for (int e = 0; e < 16; ++e) {
            float x  = qv + acc[nf][e];
            float ex = __expf(2.f * x);
            float th = 1.f - 2.f / (ex + 1.f);
            float v  = wvv * th;
            p[e] = nf ? (p[e] + v) : v;
        }
    }

    __syncthreads();                                  // all GEMM LDS reads done before reuse
    // ---- reduce over 32 lanes via LDS transpose: 128 rows x 36 floats ----
    float* ps = (float*)lds;
#pragma unroll
    for (int e = 0; e < 16; ++e) {
        int row = wave * 32 + (e & 3) + 8 * (e >> 2) + 4 * g;
        ps[row * 36 + l31] = p[e];
    }
    __syncthreads();
    {
        int rr   = tid & 127;
        int half = tid >> 7;
        const float* myrow = ps + rr * 36 + half * 16;
        float rsum = 0.f;
#pragma unroll
        for (int j = 0; j < 4; ++j) {
            float4 v = *(const float4*)(myrow + j * 4);
            rsum += (v.x + v.y) + (v.z + v.w);
        }
        float* pf = (float*)(lds + 18432);            // 256 floats
        pf[half * 128 + rr] = rsum;
        __syncthreads();
        if (tid < 128) {
            float v = pf[tid] + pf[128 + tid];
            int s = s0 + tid;
            part[((size_t)b * S_ + s) * 4 + nt] = v;
        }
    }
}

// ---------------- masked softmax over S per batch row (sums 4 partials) ----------------
__global__ void softmax_kernel(const float* __restrict__ part, const int* __restrict__ mask,
                               const float* __restrict__ bvp, float* __restrict__ attn) {
    __shared__ float red[8];
    int b = blockIdx.x, tid = threadIdx.x;         // 512 threads, 8 waves
    int wid = tid >> 6, lane = tid & 63;
    float bv0 = bvp[0];
    float vals[8];
    float mx = -3.4e38f;
#pragma unroll
    for (int i = 0; i < 8; ++i) {
        int s = i * 512 + tid;
        float4 v = *(const float4*)(part + ((size_t)b * S_ + s) * 4);
        float sc = (v.x + v.y) + (v.z + v.w) + bv0;
        sc = mask[(size_t)b * S_ + s] ? sc : NEG_INF_;
        vals[i] = sc;
        mx = fmaxf(mx, sc);
    }
#pragma unroll
    for (int off = 1; off < 64; off <<= 1) mx = fmaxf(mx, __shfl_xor(mx, off));
    if (lane == 0) red[wid] = mx;
    __syncthreads();
    mx = red[0];
#pragma unroll
    for (int w = 1; w < 8; ++w) mx = fmaxf(mx, red[w]);
    __syncthreads();
    float sum = 0.f;
#pragma unroll
    for (int i = 0; i < 8; ++i) { vals[i] = __expf(vals[i] - mx); sum += vals[i]; }
#pragma unroll
    for (int off = 1; off < 64; off <<= 1) sum += __shfl_xor(sum, off);
    if (lane == 0) red[wid] = sum;
    __syncthreads();
    sum = red[0] + red[1] + red[2] + red[3] + red[4] + red[5] + red[6] + red[7];
    float inv = 1.f / sum;
#pragma unroll
    for (int i = 0; i < 8; ++i) attn[(size_t)b * S_ + i * 512 + tid] = vals[i] * inv;
}

// ---------------- context partial sums: part[c][b][e] ----------------
__global__ void ctx_partial(const float* __restrict__ attn, const float* __restrict__ enc,
                            float* __restrict__ part) {
    __shared__ float a[256];
    int c = blockIdx.x, b = blockIdx.y, t = threadIdx.x;   // 256 threads
    a[t] = attn[(size_t)b * S_ + c * 256 + t];
    __syncthreads();
    const float* ep = enc + (size_t)b * S_ * E_ + (size_t)c * 256 * E_ + t * 2;
    float x = 0.f, y = 0.f;
#pragma unroll 4
    for (int s = 0; s < 256; ++s) {
        float2 v = *(const float2*)(ep + (size_t)s * E_);
        x += a[s] * v.x;
        y += a[s] * v.y;
    }
    float* o = part + ((size_t)c * B_ + b) * E_ + t * 2;
    o[0] = x; o[1] = y;
}

__global__ void ctx_reduce(const float* __restrict__ part, float* __restrict__ ctx) {
    int idx = blockIdx.x * 256 + threadIdx.x;       // 0..32767
    float s = 0.f;
#pragma unroll
    for (int c = 0; c < 16; ++c) s += part[(size_t)c * (B_ * E_) + idx];
    ctx[idx] = s;
}

extern "C" void kernel_launch(void* const* d_in, const int* in_sizes, int n_in,
                              void* d_out, int out_size, void* d_ws, size_t ws_size,
                              hipStream_t stream) {
    const float* hidden = (const float*)d_in[0];
    const float* enc    = (const float*)d_in[1];
    const int*   mask   = (const int*)d_in[2];
    const float* Wq     = (const float*)d_in[3];
    const float* bq     = (const float*)d_in[4];
    const float* Wk     = (const float*)d_in[5];
    const float* bk     = (const float*)d_in[6];
    const float* Wv     = (const float*)d_in[7];
    const float* bv     = (const float*)d_in[8];

    float* out  = (float*)d_out;               // [B*E context][B*S attn]
    char*  ws   = (char*)d_ws;
    float*          qbuf   = (float*)ws;                         // 131072 B
    unsigned short* wkt    = (unsigned short*)(ws + 131072);     // 524288 B
    float*          pscore = (float*)(ws + 655360);              // 4 MB [b][s][4]
    float*          cpart  = (float*)(ws + 655360);              // aliases pscore (after softmax)

    float* ctx  = out;
    float* attn = out + B_ * E_;

    prep_wkt<<<1024, 256, 0, stream>>>(Wk, wkt);
    prep_qb<<<64, 256, 0, stream>>>(hidden, Wq, bq, bk, qbuf);
    scores_kernel<<<8192, 256, 0, stream>>>(enc, wkt, qbuf, Wv, pscore);
    softmax_kernel<<<64, 512, 0, stream>>>(pscore, mask, bv, attn);
    ctx_partial<<<dim3(16, 64), 256, 0, stream>>>(attn, enc, cpart);
    ctx_reduce<<<128, 256, 0, stream>>>(cpart, ctx);
}

// Round 11
// 484.958 us; speedup vs baseline: 1.1978x; 1.1978x over previous
//
#include <hip/hip_runtime.h>
#include <hip/hip_bf16.h>

#define B_ 64
#define S_ 4096
#define H_ 512
#define E_ 512
#define NEG_INF_ -1e10f

typedef __attribute__((ext_vector_type(8))) short short8;
typedef __attribute__((ext_vector_type(16))) float f32x16;

static __device__ __forceinline__ unsigned short f2bf(float f) {
    union { float f; unsigned u; } v; v.f = f;
    unsigned x = v.u;
    x += 0x7FFFu + ((x >> 16) & 1u);   // round-to-nearest-even
    return (unsigned short)(x >> 16);
}

// vendor RNE pair conversion (verified r3/r5-r10: absmax 4.9e-4)
static __device__ __forceinline__ unsigned pk2(float lo, float hi) {
    float2 f; f.x = lo; f.y = hi;
    union { __hip_bfloat162 h; unsigned u; } c;
    c.h = __float22bfloat162_rn(f);
    return c.u;
}

static __device__ __forceinline__ void gload_lds16(const void* g, void* l) {
    __builtin_amdgcn_global_load_lds(
        (const __attribute__((address_space(1))) void*)g,
        (__attribute__((address_space(3))) void*)l, 16, 0, 0);
}

#define VMCNT8  do { asm volatile("s_waitcnt vmcnt(8)"  ::: "memory"); __builtin_amdgcn_sched_barrier(0); } while (0)
#define VMCNT0  do { asm volatile("s_waitcnt vmcnt(0)"  ::: "memory"); __builtin_amdgcn_sched_barrier(0); } while (0)

// ---------------- prep: Wkt[h][e] = bf16(Wk[e][h]) ----------------
__global__ void prep_wkt(const float* __restrict__ wk, unsigned short* __restrict__ wkt) {
    int idx = blockIdx.x * 256 + threadIdx.x;
    int h = idx >> 9, e = idx & 511;
    wkt[idx] = f2bf(wk[e * H_ + h]);
}

// ---------------- prep: qb[b][h] = hidden[b]@Wq[:,h] + bq[h] + bk[h] ----------------
__global__ void prep_qb(const float* __restrict__ hidden, const float* __restrict__ wq,
                        const float* __restrict__ bq, const float* __restrict__ bk,
                        float* __restrict__ qb) {
    __shared__ float hid[H_];
    int b = blockIdx.x, t = threadIdx.x;           // 256 threads
    hid[t]       = hidden[b * H_ + t];
    hid[t + 256] = hidden[b * H_ + t + 256];
    __syncthreads();
    for (int hh = t; hh < H_; hh += 256) {
        float s = 0.f;
        for (int e = 0; e < H_; ++e) s += hid[e] * wq[e * H_ + hh];
        qb[b * H_ + hh] = s + bq[hh] + bk[hh];
    }
}

// ---------------- main: FINAL scores for one 128-row s-tile (full N=512) ----------------
// grid 2048 = (b, s-tile 128). block 512 thr = 8 waves: (wr 0..3 M-strip) x (wc 0..1 N-half).
// Key change vs r5-r10: NO n-tile siblings -> A (enc) crosses the vmem pipe ONCE
// (per-unit-work vmem bytes halved; the r5-r10 invariant ~350us was vmem-sector-bound).
// A: direct-to-fragment f32 loads (2 reg sets, depth-2) -> pk2 -> af. No A LDS.
// B: full 512n x 32k per kc = 32 KB DMA, ring-3, XOR layout per 128-n quarter [r5+: 0-conflict].
// One s_barrier per kc, counted vmcnt(8).
__global__ __launch_bounds__(512, 2) void scores_kernel(
    const float* __restrict__ enc, const unsigned short* __restrict__ wkt,
    const float* __restrict__ qb, const float* __restrict__ wv,
    float* __restrict__ scores)
{
    __shared__ char lds[98304];   // B ring: 3 x 32KB; epilogue reuses [0, 38912)

    int id = blockIdx.x;
    int b  = id >> 5;
    int st = id & 31;
    int s0 = st * 128;

    const int tid  = threadIdx.x;
    const int lane = tid & 63;
    const int wave = tid >> 6;       // 0..7
    const int wr   = wave >> 1;      // M-strip 0..3
    const int wc   = wave & 1;       // N-half 0..1
    const int l31  = lane & 31;
    const int g    = lane >> 5;

    // A: lane-private fragment row pointer (row = s0 + wr*32 + l31, k base g*8)
    const float* aRow = enc + ((size_t)b * S_ + s0 + wr * 32 + l31) * E_ + g * 8;

    auto loadA = [&](int kc, float4 (&rg)[4]) {
        const float* p = aRow + kc * 32;
        rg[0] = *(const float4*)(p);          // ks=0
        rg[1] = *(const float4*)(p + 4);
        rg[2] = *(const float4*)(p + 16);     // ks=1
        rg[3] = *(const float4*)(p + 20);
    };
    // B stage: 512n x 32k = 32KB = 2048 x 16B. Wave w: quarter q=w>>1, half h=w&1, 4 instrs.
    // Within quarter (128n x 32k, 8KB): gi = h*256 + p*64 + lane; sn=gi>>4, ss=gi&15,
    // sl=ss^(sn&15); n = q*128 + (sl>>2)*32 + sn; k = kc*32 + (sl&3)*8; dest = qbase + gi*16.
    auto stageB = [&](int kc, char* buf) {
        char* qbase = buf + (wave >> 1) * 8192;
        int   h     = wave & 1;
#pragma unroll
        for (int p = 0; p < 4; ++p) {
            int gi0 = h * 256 + p * 64;
            char* db = qbase + gi0 * 16;               // wave-uniform dest
            int gi = gi0 + lane;
            int sn = gi >> 4, ss = gi & 15;
            int sl = ss ^ (sn & 15);
            int n  = (wave >> 1) * 128 + (sl >> 2) * 32 + sn;
            const unsigned short* gp = wkt + (size_t)n * 512 + kc * 32 + (sl & 3) * 8;
            gload_lds16(gp, db);
        }
    };

    f32x16 acc[8];
#pragma unroll
    for (int nf = 0; nf < 8; ++nf)
#pragma unroll
        for (int e = 0; e < 16; ++e) acc[nf][e] = 0.f;

    float4 ra[4], rb[4];

    // prologue: depth-2, stage FIFO = [B(4), A(4)] -> 8 vm-ops per stage, 16 in flight
    stageB(0, lds);          loadA(0, ra);
    stageB(1, lds + 32768);  loadA(1, rb);

    int cur = 0, nxt = 2;                      // read buf, stage-ahead buf (ring-3)
    for (int kc = 0; kc < 16; ++kc) {
        if (kc < 15) { VMCNT8; } else { VMCNT0; }     // stage kc resident
        // convert A(kc) -> fragments (reg-only, pre-barrier)
        short8 af[2];
        {
            union { short8 s; unsigned u[4]; } u0, u1;
            if (kc & 1) {
                u0.u[0] = pk2(rb[0].x, rb[0].y); u0.u[1] = pk2(rb[0].z, rb[0].w);
                u0.u[2] = pk2(rb[1].x, rb[1].y); u0.u[3] = pk2(rb[1].z, rb[1].w);
                u1.u[0] = pk2(rb[2].x, rb[2].y); u1.u[1] = pk2(rb[2].z, rb[2].w);
                u1.u[2] = pk2(rb[3].x, rb[3].y); u1.u[3] = pk2(rb[3].z, rb[3].w);
            } else {
                u0.u[0] = pk2(ra[0].x, ra[0].y); u0.u[1] = pk2(ra[0].z, ra[0].w);
                u0.u[2] = pk2(ra[1].x, ra[1].y); u0.u[3] = pk2(ra[1].z, ra[1].w);
                u1.u[0] = pk2(ra[2].x, ra[2].y); u1.u[1] = pk2(ra[2].z, ra[2].w);
                u1.u[2] = pk2(ra[3].x, ra[3].y); u1.u[3] = pk2(ra[3].z, ra[3].w);
            }
            af[0] = u0.s; af[1] = u1.s;
        }
        __builtin_amdgcn_s_barrier();                 // B(kc) fully resident
        __builtin_amdgcn_sched_barrier(0);
        if (kc < 14) {                                // issue stage kc+2 into ring slot nxt
            stageB(kc + 2, lds + nxt * 32768);
            if (kc & 1) loadA(kc + 2, rb); else loadA(kc + 2, ra);
        }
        const char* Bb = lds + cur * 32768;
#pragma unroll
        for (int ks = 0; ks < 2; ++ks) {
#pragma unroll
            for (int nf = 0; nf < 8; ++nf) {
                const char* qb_ = Bb + (wc * 2 + (nf >> 2)) * 8192;
                int sl = (nf & 3) * 4 + ks * 2 + g;
                short8 bf = *(const short8*)(qb_ + l31 * 256 + ((sl ^ (l31 & 15)) << 4));
                acc[nf] = __builtin_amdgcn_mfma_f32_32x32x16_bf16(af[ks], bf, acc[nf], 0, 0, 0);
            }
        }
        cur = (cur == 2) ? 0 : cur + 1;
        nxt = (nxt == 2) ? 0 : nxt + 1;
    }

    // ---- epilogue: p[e] = sum_nf Wv[col]*tanh(qb[col]+acc[nf][e]), col = wc*256+nf*32+l31 ----
    float p[16];
#pragma unroll
    for (int nf = 0; nf < 8; ++nf) {
        int col = wc * 256 + nf * 32 + l31;
        float qv  = qb[b * H_ + col];
        float wvv = wv[col];
#pragma unroll
        for (int e = 0; e < 16; ++e) {
            float x  = qv + acc[nf][e];
            float ex = __expf(2.f * x);
            float th = 1.f - 2.f / (ex + 1.f);
            float v  = wvv * th;
            p[e] = nf ? (p[e] + v) : v;
        }
    }

    __syncthreads();                                  // all GEMM LDS reads done before reuse
    // ---- reduce 32 lanes x 2 wc-halves via LDS: ps[2][128][37] (stride 37: odd -> no conflict) ----
    float* ps = (float*)lds;
#pragma unroll
    for (int e = 0; e < 16; ++e) {
        int row = wr * 32 + (e & 3) + 8 * (e >> 2) + 4 * g;
        ps[(wc * 128 + row) * 37 + l31] = p[e];
    }
    __syncthreads();
    if (tid < 256) {
        int rr = tid & 127, h = tid >> 7;
        const float* myrow = ps + (h * 128 + rr) * 37;
        float rsum = 0.f;
#pragma unroll
        for (int j = 0; j < 32; ++j) rsum += myrow[j];
        float* pf = (float*)(lds + 37888);            // 256 floats
        pf[h * 128 + rr] = rsum;
    }
    __syncthreads();
    if (tid < 128) {
        float* pf = (float*)(lds + 37888);
        scores[(size_t)b * S_ + s0 + tid] = pf[tid] + pf[128 + tid];
    }
}

// ---------------- masked softmax over S per batch row ----------------
__global__ void softmax_kernel(const float* __restrict__ scores, const int* __restrict__ mask,
                               const float* __restrict__ bvp, float* __restrict__ attn) {
    __shared__ float red[8];
    int b = blockIdx.x, tid = threadIdx.x;         // 512 threads, 8 waves
    int wid = tid >> 6, lane = tid & 63;
    float bv0 = bvp[0];
    float vals[8];
    float mx = -3.4e38f;
#pragma unroll
    for (int i = 0; i < 8; ++i) {
        int s = i * 512 + tid;
        float sc = scores[(size_t)b * S_ + s] + bv0;
        sc = mask[(size_t)b * S_ + s] ? sc : NEG_INF_;
        vals[i] = sc;
        mx = fmaxf(mx, sc);
    }
#pragma unroll
    for (int off = 1; off < 64; off <<= 1) mx = fmaxf(mx, __shfl_xor(mx, off));
    if (lane == 0) red[wid] = mx;
    __syncthreads();
    mx = red[0];
#pragma unroll
    for (int w = 1; w < 8; ++w) mx = fmaxf(mx, red[w]);
    __syncthreads();
    float sum = 0.f;
#pragma unroll
    for (int i = 0; i < 8; ++i) { vals[i] = __expf(vals[i] - mx); sum += vals[i]; }
#pragma unroll
    for (int off = 1; off < 64; off <<= 1) sum += __shfl_xor(sum, off);
    if (lane == 0) red[wid] = sum;
    __syncthreads();
    sum = red[0] + red[1] + red[2] + red[3] + red[4] + red[5] + red[6] + red[7];
    float inv = 1.f / sum;
#pragma unroll
    for (int i = 0; i < 8; ++i) attn[(size_t)b * S_ + i * 512 + tid] = vals[i] * inv;
}

// ---------------- context partial sums: part[c][b][e] ----------------
__global__ void ctx_partial(const float* __restrict__ attn, const float* __restrict__ enc,
                            float* __restrict__ part) {
    __shared__ float a[256];
    int c = blockIdx.x, b = blockIdx.y, t = threadIdx.x;   // 256 threads
    a[t] = attn[(size_t)b * S_ + c * 256 + t];
    __syncthreads();
    const float* ep = enc + (size_t)b * S_ * E_ + (size_t)c * 256 * E_ + t * 2;
    float x = 0.f, y = 0.f;
#pragma unroll 4
    for (int s = 0; s < 256; ++s) {
        float2 v = *(const float2*)(ep + (size_t)s * E_);
        x += a[s] * v.x;
        y += a[s] * v.y;
    }
    float* o = part + ((size_t)c * B_ + b) * E_ + t * 2;
    o[0] = x; o[1] = y;
}

__global__ void ctx_reduce(const float* __restrict__ part, float* __restrict__ ctx) {
    int idx = blockIdx.x * 256 + threadIdx.x;       // 0..32767
    float s = 0.f;
#pragma unroll
    for (int c = 0; c < 16; ++c) s += part[(size_t)c * (B_ * E_) + idx];
    ctx[idx] = s;
}

extern "C" void kernel_launch(void* const* d_in, const int* in_sizes, int n_in,
                              void* d_out, int out_size, void* d_ws, size_t ws_size,
                              hipStream_t stream) {
    const float* hidden = (const float*)d_in[0];
    const float* enc    = (const float*)d_in[1];
    const int*   mask   = (const int*)d_in[2];
    const float* Wq     = (const float*)d_in[3];
    const float* bq     = (const float*)d_in[4];
    const float* Wk     = (const float*)d_in[5];
    const float* bk     = (const float*)d_in[6];
    const float* Wv     = (const float*)d_in[7];
    const float* bv     = (const float*)d_in[8];

    float* out  = (float*)d_out;               // [B*E context][B*S attn]
    char*  ws   = (char*)d_ws;
    float*          qbuf   = (float*)ws;                         // 131072 B
    unsigned short* wkt    = (unsigned short*)(ws + 131072);     // 524288 B
    float*          pscore = (float*)(ws + 655360);              // 1 MB [b][s]
    float*          cpart  = (float*)(ws + 655360 + 1048576);    // 2 MB [c][b][e]

    float* ctx  = out;
    float* attn = out + B_ * E_;

    prep_wkt<<<1024, 256, 0, stream>>>(Wk, wkt);
    prep_qb<<<64, 256, 0, stream>>>(hidden, Wq, bq, bk, qbuf);
    scores_kernel<<<2048, 512, 0, stream>>>(enc, wkt, qbuf, Wv, pscore);
    softmax_kernel<<<64, 512, 0, stream>>>(pscore, mask, bv, attn);
    ctx_partial<<<dim3(16, 64), 256, 0, stream>>>(attn, enc, cpart);
    ctx_reduce<<<128, 256, 0, stream>>>(cpart, ctx);
}